// Round 1
// baseline (47.977 us; speedup 1.0000x reference)
//
#include <hip/hip_runtime.h>

// LIF spike forward (value path only):
//   mem = mem*TAU + x[t]; spike = mem > THRESH; mem -= spike*THRESH
// x: [T*B, C, H, W] fp32 viewed as [T][N] with N = B*C*H*W.
// Purely elementwise per n in [0,N); sequential only over T=8.
// Memory-bound: 256 MiB total traffic -> ~43us floor at 6.3 TB/s.

#define LIF_T 8
#define LIF_THRESH 1.0f
#define LIF_TAU 0.5f

__global__ __launch_bounds__(256) void lif_spike_kernel(
    const float4* __restrict__ x, float4* __restrict__ out, int nv4) {
    int stride = gridDim.x * blockDim.x;
    for (int i = blockIdx.x * blockDim.x + threadIdx.x; i < nv4; i += stride) {
        float4 mem = make_float4(0.f, 0.f, 0.f, 0.f);
        #pragma unroll
        for (int t = 0; t < LIF_T; ++t) {
            size_t off = (size_t)t * (size_t)nv4 + (size_t)i;
            float4 xt = x[off];
            mem.x = mem.x * LIF_TAU + xt.x;
            mem.y = mem.y * LIF_TAU + xt.y;
            mem.z = mem.z * LIF_TAU + xt.z;
            mem.w = mem.w * LIF_TAU + xt.w;
            float4 s;
            s.x = mem.x > LIF_THRESH ? 1.0f : 0.0f;
            s.y = mem.y > LIF_THRESH ? 1.0f : 0.0f;
            s.z = mem.z > LIF_THRESH ? 1.0f : 0.0f;
            s.w = mem.w > LIF_THRESH ? 1.0f : 0.0f;
            out[off] = s;
            mem.x -= s.x * LIF_THRESH;
            mem.y -= s.y * LIF_THRESH;
            mem.z -= s.z * LIF_THRESH;
            mem.w -= s.w * LIF_THRESH;
        }
    }
}

extern "C" void kernel_launch(void* const* d_in, const int* in_sizes, int n_in,
                              void* d_out, int out_size, void* d_ws, size_t ws_size,
                              hipStream_t stream) {
    const float* x = (const float*)d_in[0];
    float* out = (float*)d_out;

    int total = in_sizes[0];           // T * B * C * H * W = 33,554,432
    int n_per_t = total / LIF_T;       // 4,194,304 (multiple of 4)
    int nv4 = n_per_t / 4;             // 1,048,576 float4 lanes

    int block = 256;
    int want = (nv4 + block - 1) / block;   // 4096
    int grid = want < 2048 ? want : 2048;   // grid-stride, 2 items/thread

    lif_spike_kernel<<<grid, block, 0, stream>>>(
        (const float4*)x, (float4*)out, nv4);
}

// Round 2
// 46.687 us; speedup vs baseline: 1.0276x; 1.0276x over previous
//
#include <hip/hip_runtime.h>

// LIF spike forward (value path only):
//   mem = mem*TAU + x[t]; spike = mem > THRESH; mem -= spike*THRESH
// x: [T*B, C, H, W] fp32 viewed as [T][N], N = 4,194,304. Elementwise per n,
// sequential over T=8 (mem carried in registers).
//
// R1 counters: FETCH 65 MB (half of x L3-resident), WRITE 135 MB.
// x(128MiB)+out(128MiB) == L3(256MiB) -> writes thrash x out of L3.
// Fix: non-temporal stores for out (write-once, never re-read) so x stays
// fully L3-resident across graph replays. Expect HBM ~= write stream only.

#define LIF_T 8
#define LIF_THRESH 1.0f
#define LIF_TAU 0.5f

typedef float f32x4 __attribute__((ext_vector_type(4)));

__global__ __launch_bounds__(256) void lif_spike_kernel(
    const f32x4* __restrict__ x, f32x4* __restrict__ out, int nv4) {
    int i = blockIdx.x * blockDim.x + threadIdx.x;
    if (i >= nv4) return;

    f32x4 mem = {0.f, 0.f, 0.f, 0.f};
    #pragma unroll
    for (int t = 0; t < LIF_T; ++t) {
        size_t off = (size_t)t * (size_t)nv4 + (size_t)i;
        f32x4 xt = x[off];                      // normal load: keep x in L3
        mem = mem * LIF_TAU + xt;
        f32x4 s;
        s.x = mem.x > LIF_THRESH ? 1.0f : 0.0f;
        s.y = mem.y > LIF_THRESH ? 1.0f : 0.0f;
        s.z = mem.z > LIF_THRESH ? 1.0f : 0.0f;
        s.w = mem.w > LIF_THRESH ? 1.0f : 0.0f;
        __builtin_nontemporal_store(s, &out[off]);  // nt: don't pollute L3
        mem = mem - s * LIF_THRESH;
    }
}

extern "C" void kernel_launch(void* const* d_in, const int* in_sizes, int n_in,
                              void* d_out, int out_size, void* d_ws, size_t ws_size,
                              hipStream_t stream) {
    const float* x = (const float*)d_in[0];
    float* out = (float*)d_out;

    int total = in_sizes[0];           // 33,554,432
    int n_per_t = total / LIF_T;       // 4,194,304
    int nv4 = n_per_t / 4;             // 1,048,576 float4 elements

    int block = 256;
    int grid = (nv4 + block - 1) / block;   // 4096 blocks, 1 elem/thread

    lif_spike_kernel<<<grid, block, 0, stream>>>(
        (const f32x4*)x, (f32x4*)out, nv4);
}

// Round 3
// 45.223 us; speedup vs baseline: 1.0609x; 1.0324x over previous
//
#include <hip/hip_runtime.h>

// LIF spike forward (value path only):
//   mem = mem*TAU + x[t]; spike = mem > THRESH; mem -= spike*THRESH
// x: [T*B, C, H, W] fp32 viewed as [T][N], N = 4,194,304. Elementwise per n,
// sequential over T=8 (mem carried in registers).
//
// R2 post-mortem: VGPR_Count=24 -> compiler serialized the t-loop
// (1 outstanding load/wave -> latency-bound at ~4.3 TB/s effective).
// Fix: hoist ALL 8 loads before the compute chain (loads are independent
// of mem) -> 8 outstanding 1KiB loads per wave, latency fully hidden.

#define LIF_T 8
#define LIF_THRESH 1.0f
#define LIF_TAU 0.5f

typedef float f32x4 __attribute__((ext_vector_type(4)));

__global__ __launch_bounds__(256) void lif_spike_kernel(
    const f32x4* __restrict__ x, f32x4* __restrict__ out, int nv4) {
    int i = blockIdx.x * blockDim.x + threadIdx.x;
    if (i >= nv4) return;

    // Issue all 8 loads up-front (independent -> 8 in flight per wave).
    f32x4 xv0 = x[(size_t)0 * nv4 + i];
    f32x4 xv1 = x[(size_t)1 * nv4 + i];
    f32x4 xv2 = x[(size_t)2 * nv4 + i];
    f32x4 xv3 = x[(size_t)3 * nv4 + i];
    f32x4 xv4 = x[(size_t)4 * nv4 + i];
    f32x4 xv5 = x[(size_t)5 * nv4 + i];
    f32x4 xv6 = x[(size_t)6 * nv4 + i];
    f32x4 xv7 = x[(size_t)7 * nv4 + i];

    f32x4 mem = {0.f, 0.f, 0.f, 0.f};
    f32x4 xv[LIF_T] = {xv0, xv1, xv2, xv3, xv4, xv5, xv6, xv7};

    #pragma unroll
    for (int t = 0; t < LIF_T; ++t) {
        mem = mem * LIF_TAU + xv[t];
        f32x4 s;
        s.x = mem.x > LIF_THRESH ? 1.0f : 0.0f;
        s.y = mem.y > LIF_THRESH ? 1.0f : 0.0f;
        s.z = mem.z > LIF_THRESH ? 1.0f : 0.0f;
        s.w = mem.w > LIF_THRESH ? 1.0f : 0.0f;
        __builtin_nontemporal_store(s, &out[(size_t)t * nv4 + i]);
        mem = mem - s * LIF_THRESH;
    }
}

extern "C" void kernel_launch(void* const* d_in, const int* in_sizes, int n_in,
                              void* d_out, int out_size, void* d_ws, size_t ws_size,
                              hipStream_t stream) {
    const float* x = (const float*)d_in[0];
    float* out = (float*)d_out;

    int total = in_sizes[0];           // 33,554,432
    int n_per_t = total / LIF_T;       // 4,194,304
    int nv4 = n_per_t / 4;             // 1,048,576 float4 elements

    int block = 256;
    int grid = (nv4 + block - 1) / block;   // 4096 blocks, 1 elem/thread

    lif_spike_kernel<<<grid, block, 0, stream>>>(
        (const f32x4*)x, (f32x4*)out, nv4);
}